// Round 12
// baseline (830.338 us; speedup 1.0000x reference)
//
#include <hip/hip_runtime.h>
#include <cstddef>
#include <cstdint>

#define E_EDGES 1000000
#define NU 100000
#define NM 20000
#define DU 128
#define DM 404      // D_MOVIE
#define HIDDIM 256
#define OUTDIM 128
#define XMW 544     // concat row width: 128 + 404 + 12 pad  (17*32)

// CSR build (bucketed counting sort, no global atomics)
#define NBLK 64
#define EPB 15625
#define NBKT_M 313
#define NBKT_U 196

typedef short bf8_t __attribute__((ext_vector_type(8)));
typedef float f32x4 __attribute__((ext_vector_type(4)));
typedef unsigned short u16x8 __attribute__((ext_vector_type(8)));

__device__ __forceinline__ float b2f(unsigned short u) {
  union { unsigned int i; float f; } x; x.i = ((unsigned int)u) << 16; return x.f;
}
__device__ __forceinline__ unsigned short f2b(float f) {
  union { float f; unsigned int i; } x; x.f = f;
  unsigned int r = x.i + 0x7FFFu + ((x.i >> 16) & 1u);  // RTNE
  return (unsigned short)(r >> 16);
}
__device__ __forceinline__ int ntl_i32(const int* p) { return __builtin_nontemporal_load(p); }
__device__ __forceinline__ void nts_u16x8(unsigned short* p, u16x8 v) {
  __builtin_nontemporal_store(v, reinterpret_cast<u16x8*>(p));
}
__device__ __forceinline__ void nts_f32x4(float* p, f32x4 v) {
  __builtin_nontemporal_store(v, reinterpret_cast<f32x4*>(p));
}

#define GLOAD_LDS16(gp, lp)                                                      \
  __builtin_amdgcn_global_load_lds(                                              \
      (const __attribute__((address_space(1))) unsigned int*)(gp),               \
      (__attribute__((address_space(3))) unsigned int*)(lp), 16, 0, 0)

// ================= passA: bucket counts (blocks 0..127) + prep (rest) =================
#define PRA 3200000
#define PRB 5280000
#define PRC 5722368
__global__ __launch_bounds__(256) void passA_kernel(
    const int* __restrict__ esrc, const int* __restrict__ edst,
    int* __restrict__ cnt_m, int* __restrict__ cnt_u,
    const float* __restrict__ x_user, unsigned short* __restrict__ xu_bf,
    const float* __restrict__ x_movie, unsigned short* __restrict__ xmcat,
    const float* __restrict__ w1_rm_l, const float* __restrict__ w1_rm_r,
    const float* __restrict__ w1_mu_l, const float* __restrict__ w1_mu_r,
    const float* __restrict__ w2_rm_l, const float* __restrict__ w2_mu_r,
    const float* __restrict__ w2_mu_l, const float* __restrict__ w2_rm_r,
    unsigned short* __restrict__ wL1, unsigned short* __restrict__ w1mur,
    unsigned short* __restrict__ wL2u, unsigned short* __restrict__ w2mul,
    unsigned short* __restrict__ w2rmr) {
  __shared__ int hist[NBKT_M];
  const int bx = blockIdx.x;
  if (bx < NBLK) {
    for (int i = threadIdx.x; i < NBKT_M; i += 256) hist[i] = 0;
    __syncthreads();
    const int base = bx * EPB, end = base + EPB;
    for (int i = base + threadIdx.x; i < end; i += 256)
      atomicAdd(&hist[edst[i] >> 6], 1);
    __syncthreads();
    for (int i = threadIdx.x; i < NBKT_M; i += 256)
      cnt_m[bx * NBKT_M + i] = hist[i];
    return;
  }
  if (bx < 2 * NBLK) {
    const int b = bx - NBLK;
    for (int i = threadIdx.x; i < NBKT_U; i += 256) hist[i] = 0;
    __syncthreads();
    const int base = b * EPB, end = base + EPB;
    for (int i = base + threadIdx.x; i < end; i += 256)
      atomicAdd(&hist[esrc[i] >> 9], 1);
    __syncthreads();
    for (int i = threadIdx.x; i < NBKT_U; i += 256)
      cnt_u[b * NBKT_U + i] = hist[i];
    return;
  }
  int j = (bx - 2 * NBLK) * 256 + threadIdx.x;
  if (j < PRA) {
    float4 v = reinterpret_cast<const float4*>(x_user)[j];
    ushort4 o;
    o.x = f2b(v.x); o.y = f2b(v.y); o.z = f2b(v.z); o.w = f2b(v.w);
    reinterpret_cast<ushort4*>(xu_bf)[j] = o;
  } else if (j < PRB) {
    int q = j - PRA;
    int row = q / 104, c4 = (q % 104) * 4;
    ushort4 o;
    if (c4 < DM) {
      float4 v = *reinterpret_cast<const float4*>(&x_movie[(size_t)row * DM + c4]);
      o.x = f2b(v.x); o.y = f2b(v.y); o.z = f2b(v.z); o.w = f2b(v.w);
    } else {
      o.x = o.y = o.z = o.w = 0;
    }
    *reinterpret_cast<ushort4*>(&xmcat[(size_t)row * XMW + 128 + c4]) = o;
  } else if (j < PRC) {
    int q = j - PRB;
    if (q < 278528) {
      int n = q / 544, k = q % 544;
      float v = 0.f;
      if (n < 256) {
        if (k < 128) v = w1_rm_l[(size_t)k * 256 + n];
        else if (k < 532) v = w1_rm_r[(size_t)(k - 128) * 256 + n];
      } else {
        if (k >= 128 && k < 532) v = w1_mu_l[(size_t)(k - 128) * 256 + (n - 256)];
      }
      wL1[q] = f2b(v);
    } else if (q < 311296) {
      int p = q - 278528; int n = p / 128, k = p % 128;
      w1mur[p] = f2b(w1_mu_r[(size_t)k * 256 + n]);
    } else if (q < 376832) {
      int p = q - 311296; int n = p / 256, k = p % 256;
      float v = (n < 128) ? w2_rm_l[(size_t)k * 128 + n] : w2_mu_r[(size_t)k * 128 + (n - 128)];
      wL2u[p] = f2b(v);
    } else if (q < 409600) {
      int p = q - 376832; int n = p / 256, k = p % 256;
      w2mul[p] = f2b(w2_mu_l[(size_t)k * 128 + n]);
    } else {
      int p = q - 409600; int n = p / 256, k = p % 256;
      w2rmr[p] = f2b(w2_rm_r[(size_t)k * 128 + n]);
    }
  }
}

// ================= scanAB =================
__global__ __launch_bounds__(256) void scanAB_kernel(
    int* __restrict__ cnt_m, int* __restrict__ base_m, int* __restrict__ bo_m,
    int* __restrict__ cnt_u, int* __restrict__ base_u, int* __restrict__ bo_u) {
  const int NB = blockIdx.x ? NBKT_U : NBKT_M;
  const int* cnt = blockIdx.x ? cnt_u : cnt_m;
  int* basep = blockIdx.x ? base_u : base_m;
  int* bo = blockIdx.x ? bo_u : bo_m;
  __shared__ int tot[NBKT_M];
  for (int B = threadIdx.x; B < NB; B += 256) {
    int s = 0;
    for (int b = 0; b < NBLK; ++b) {
      int c = cnt[b * NB + B];
      basep[b * NB + B] = s;
      s += c;
    }
    tot[B] = s;
  }
  __syncthreads();
  if (threadIdx.x < 64) {
    const int lane = threadIdx.x;
    int carry = 0;
    for (int c0 = 0; c0 < NB; c0 += 64) {
      int v = (c0 + lane < NB) ? tot[c0 + lane] : 0;
      int s = v;
#pragma unroll
      for (int d = 1; d < 64; d <<= 1) {
        int t = __shfl_up(s, d, 64);
        if (lane >= d) s += t;
      }
      if (c0 + lane < NB) bo[c0 + lane] = carry + s - v;
      carry += __shfl(s, 63, 64);
    }
    if (lane == 0) bo[NB] = carry;
  }
  __syncthreads();
  for (int B = threadIdx.x; B < NB; B += 256) {
    const int b0 = bo[B];
    for (int b = 0; b < NBLK; ++b) basep[b * NB + B] += b0;
  }
}

// ================= shared GEMM core =================
template <int MODE>
__device__ __forceinline__ void gemm_core(
    const unsigned short* __restrict__ A, int lda,
    const unsigned short* __restrict__ Bt, int ldb, int K,
    const unsigned short* __restrict__ elem, const float* __restrict__ bias,
    void* __restrict__ outA, int M, int bx, int by,
    unsigned short* Alds, unsigned short* Blds) {
  const int tid = threadIdx.x;
  const int w = tid >> 6, l = tid & 63;
  const int row0 = bx * 128;
  const int col0 = by * 128;
  const int wr = w >> 1, wc = w & 1;

  f32x4 acc[4][4] = {};

  int ar0 = row0 + w * 32 + (l >> 2);
  int ar1 = ar0 + 16;
  if (ar0 >= M) ar0 = M - 1;
  if (ar1 >= M) ar1 = M - 1;
  const size_t aoff0 = (size_t)ar0 * lda + (l & 3) * 8;
  const size_t aoff1 = (size_t)ar1 * lda + (l & 3) * 8;
  const int nr0 = col0 + w * 32 + (l >> 2);
  const size_t boff0 = (size_t)nr0 * ldb + (l & 3) * 8;
  const size_t boff1 = (size_t)(nr0 + 16) * ldb + (l & 3) * 8;
  unsigned short* aldsb = &Alds[w * 1024];
  unsigned short* bldsb = &Blds[w * 1024];

  for (int k0 = 0; k0 < K; k0 += 32) {
    GLOAD_LDS16(A + aoff0 + k0, aldsb);
    GLOAD_LDS16(A + aoff1 + k0, aldsb + 512);
    GLOAD_LDS16(Bt + boff0 + k0, bldsb);
    GLOAD_LDS16(Bt + boff1 + k0, bldsb + 512);
    __syncthreads();
    bf8_t af[4], bfr[4];
#pragma unroll
    for (int mi = 0; mi < 4; ++mi)
      af[mi] = *reinterpret_cast<const bf8_t*>(&Alds[(wr * 64 + mi * 16 + (l & 15)) * 32 + (l >> 4) * 8]);
#pragma unroll
    for (int nj = 0; nj < 4; ++nj)
      bfr[nj] = *reinterpret_cast<const bf8_t*>(&Blds[(wc * 64 + nj * 16 + (l & 15)) * 32 + (l >> 4) * 8]);
#pragma unroll
    for (int mi = 0; mi < 4; ++mi)
#pragma unroll
      for (int nj = 0; nj < 4; ++nj)
        acc[mi][nj] = __builtin_amdgcn_mfma_f32_16x16x32_bf16(af[mi], bfr[nj], acc[mi][nj], 0, 0, 0);
    __syncthreads();
  }

#pragma unroll
  for (int mi = 0; mi < 4; ++mi) {
    const int rbase = row0 + wr * 64 + mi * 16 + ((l >> 4) << 2);
#pragma unroll
    for (int nj = 0; nj < 4; ++nj) {
      const int col = col0 + wc * 64 + nj * 16 + (l & 15);
      float bb = 0.0f;
      if constexpr (MODE == 0 || MODE == 1 || MODE == 6) bb = bias[col];
#pragma unroll
      for (int r = 0; r < 4; ++r) {
        const int row = rbase + r;
        if (row >= M) continue;
        float v = acc[mi][nj][r] + bb;
        if constexpr (MODE == 1) v += b2f(elem[(size_t)row * 256 + col]);
        if constexpr (MODE == 0 || MODE == 1) v = fmaxf(v, 0.0f);
        if constexpr (MODE == 0 || MODE == 1 || MODE == 5) {
          ((unsigned short*)outA)[(size_t)row * 256 + col] = f2b(v);
        } else if constexpr (MODE == 2) {
          ((unsigned short*)outA)[(size_t)row * 128 + col] = f2b(v);
        } else {
          ((float*)outA)[(size_t)row * 128 + col] = v;
        }
      }
    }
  }
}

// ================= passB: bucket-scatter (blocks 0..127) + t1 GEMM (rest) =================
__global__ __launch_bounds__(256) void passB_kernel(
    const int* __restrict__ esrc, const int* __restrict__ edst,
    const int* __restrict__ base_m, const int* __restrict__ base_u,
    int* __restrict__ ebuf_m, int* __restrict__ ebuf_u,
    const unsigned short* __restrict__ A, const unsigned short* __restrict__ Bt,
    unsigned short* __restrict__ t1) {
  __shared__ unsigned short Alds[128 * 32];
  __shared__ unsigned short Blds[128 * 32];
  const int bx = blockIdx.x;
  if (bx < NBLK) {
    int* cur = (int*)Alds;
    for (int i = threadIdx.x; i < NBKT_M; i += 256) cur[i] = base_m[bx * NBKT_M + i];
    __syncthreads();
    const int base = bx * EPB, end = base + EPB;
    for (int i = base + threadIdx.x; i < end; i += 256) {
      const int d = edst[i], s = esrc[i];
      const int pos = atomicAdd(&cur[d >> 6], 1);
      ebuf_m[pos] = (s << 6) | (d & 63);
    }
    return;
  }
  if (bx < 2 * NBLK) {
    const int b = bx - NBLK;
    int* cur = (int*)Alds;
    for (int i = threadIdx.x; i < NBKT_U; i += 256) cur[i] = base_u[b * NBKT_U + i];
    __syncthreads();
    const int base = b * EPB, end = base + EPB;
    for (int i = base + threadIdx.x; i < end; i += 256) {
      const int d = edst[i], s = esrc[i];
      const int pos = atomicAdd(&cur[s >> 9], 1);
      ebuf_u[pos] = (d << 9) | (s & 511);
    }
    return;
  }
  const int bi = bx - 2 * NBLK;
  gemm_core<5>(A, XMW, Bt, XMW, 416, nullptr, nullptr, t1, NM,
               bi % 157, bi / 157, Alds, Blds);
}

// ================= passC: per-bucket CSR + off =================
__global__ __launch_bounds__(256) void passC_kernel(
    const int* __restrict__ ebuf_m, const int* __restrict__ bo_m,
    int* __restrict__ off_m, int* __restrict__ csr_m,
    const int* __restrict__ ebuf_u, const int* __restrict__ bo_u,
    int* __restrict__ off_u, int* __restrict__ csr_u) {
  __shared__ int hist[512];
  const int bx = blockIdx.x;
  if (bx < NBKT_M) {
    const int B = bx;
    const int lo = bo_m[B], hi = bo_m[B + 1];
    const int nbin = (NM - B * 64 < 64) ? (NM - B * 64) : 64;
    for (int i = threadIdx.x; i < 64; i += 256) hist[i] = 0;
    __syncthreads();
    for (int i = lo + threadIdx.x; i < hi; i += 256)
      atomicAdd(&hist[ebuf_m[i] & 63], 1);
    __syncthreads();
    if (threadIdx.x < 64) {
      const int lane = threadIdx.x;
      const int v = hist[lane];
      int s = v;
#pragma unroll
      for (int d = 1; d < 64; d <<= 1) {
        int t = __shfl_up(s, d, 64);
        if (lane >= d) s += t;
      }
      const int ex = s - v;
      if (lane < nbin) off_m[B * 64 + lane] = lo + ex;
      if (B == NBKT_M - 1 && lane == 0) off_m[NM] = hi;
      hist[lane] = ex;
    }
    __syncthreads();
    for (int i = lo + threadIdx.x; i < hi; i += 256) {
      const int p = ebuf_m[i];
      const int pos = atomicAdd(&hist[p & 63], 1);
      csr_m[lo + pos] = p >> 6;
    }
    return;
  }
  const int B = bx - NBKT_M;
  const int lo = bo_u[B], hi = bo_u[B + 1];
  const int nbin = (NU - B * 512 < 512) ? (NU - B * 512) : 512;
  for (int i = threadIdx.x; i < 512; i += 256) hist[i] = 0;
  __syncthreads();
  for (int i = lo + threadIdx.x; i < hi; i += 256)
    atomicAdd(&hist[ebuf_u[i] & 511], 1);
  __syncthreads();
  if (threadIdx.x < 64) {
    const int lane = threadIdx.x;
    int carry = 0;
    for (int c0 = 0; c0 < 512; c0 += 64) {
      const int v = hist[c0 + lane];
      int s = v;
#pragma unroll
      for (int d = 1; d < 64; d <<= 1) {
        int t = __shfl_up(s, d, 64);
        if (lane >= d) s += t;
      }
      const int ex = carry + s - v;
      if (c0 + lane < nbin) off_u[B * 512 + c0 + lane] = lo + ex;
      hist[c0 + lane] = ex;
      carry += __shfl(s, 63, 64);
    }
    if (B == NBKT_U - 1 && lane == 0) off_u[NU] = hi;
  }
  __syncthreads();
  for (int i = lo + threadIdx.x; i < hi; i += 256) {
    const int p = ebuf_u[i];
    const int pos = atomicAdd(&hist[p & 511], 1);
    csr_u[lo + pos] = p >> 9;
  }
}

// ================= XCD-pinned slice gathers =================
// slice32 bf16-out: 32 cols, 4 lanes/node (16B), 64 nodes/block
__device__ __forceinline__ void gather_slice32_b16(
    const unsigned short* __restrict__ table, int tstride,
    const int* __restrict__ off, const int* __restrict__ idx,
    unsigned short* __restrict__ out, int ostride, int n, int col0, int chunk) {
  const int t = threadIdx.x;
  const int g = t >> 2;
  const int cl = col0 + (t & 3) * 8;
  const int node = chunk * 64 + g;
  if (node >= n) return;
  const int beg = ntl_i32(&off[node]), end = ntl_i32(&off[node + 1]);
  const float sc = 1.0f / fmaxf((float)(end - beg), 1.0f);
  float a[8] = {0, 0, 0, 0, 0, 0, 0, 0}, b[8] = {0, 0, 0, 0, 0, 0, 0, 0};
  int p = beg;
  for (; p + 3 < end; p += 4) {
    const int r0 = ntl_i32(&idx[p]), r1 = ntl_i32(&idx[p + 1]);
    const int r2 = ntl_i32(&idx[p + 2]), r3 = ntl_i32(&idx[p + 3]);
    u16x8 v0 = *reinterpret_cast<const u16x8*>(&table[(size_t)r0 * tstride + cl]);
    u16x8 v1 = *reinterpret_cast<const u16x8*>(&table[(size_t)r1 * tstride + cl]);
    u16x8 v2 = *reinterpret_cast<const u16x8*>(&table[(size_t)r2 * tstride + cl]);
    u16x8 v3 = *reinterpret_cast<const u16x8*>(&table[(size_t)r3 * tstride + cl]);
#pragma unroll
    for (int j = 0; j < 8; ++j) { a[j] += b2f(v0[j]); b[j] += b2f(v1[j]); }
#pragma unroll
    for (int j = 0; j < 8; ++j) { a[j] += b2f(v2[j]); b[j] += b2f(v3[j]); }
  }
  for (; p < end; ++p) {
    const int r0 = ntl_i32(&idx[p]);
    u16x8 v0 = *reinterpret_cast<const u16x8*>(&table[(size_t)r0 * tstride + cl]);
#pragma unroll
    for (int j = 0; j < 8; ++j) a[j] += b2f(v0[j]);
  }
  u16x8 o;
#pragma unroll
  for (int j = 0; j < 8; ++j) o[j] = f2b((a[j] + b[j]) * sc);
  nts_u16x8(&out[(size_t)node * ostride + cl], o);
}

// slice16 bf16-out: 16 cols, 2 lanes/node, 128 nodes/block
__device__ __forceinline__ void gather_slice16_b16(
    const unsigned short* __restrict__ table, int tstride,
    const int* __restrict__ off, const int* __restrict__ idx,
    unsigned short* __restrict__ out, int ostride, int n, int col0, int chunk) {
  const int t = threadIdx.x;
  const int g = t >> 1;
  const int cl = col0 + (t & 1) * 8;
  const int node = chunk * 128 + g;
  if (node >= n) return;
  const int beg = ntl_i32(&off[node]), end = ntl_i32(&off[node + 1]);
  const float sc = 1.0f / fmaxf((float)(end - beg), 1.0f);
  float a[8] = {0, 0, 0, 0, 0, 0, 0, 0}, b[8] = {0, 0, 0, 0, 0, 0, 0, 0};
  int p = beg;
  for (; p + 3 < end; p += 4) {
    const int r0 = ntl_i32(&idx[p]), r1 = ntl_i32(&idx[p + 1]);
    const int r2 = ntl_i32(&idx[p + 2]), r3 = ntl_i32(&idx[p + 3]);
    u16x8 v0 = *reinterpret_cast<const u16x8*>(&table[(size_t)r0 * tstride + cl]);
    u16x8 v1 = *reinterpret_cast<const u16x8*>(&table[(size_t)r1 * tstride + cl]);
    u16x8 v2 = *reinterpret_cast<const u16x8*>(&table[(size_t)r2 * tstride + cl]);
    u16x8 v3 = *reinterpret_cast<const u16x8*>(&table[(size_t)r3 * tstride + cl]);
#pragma unroll
    for (int j = 0; j < 8; ++j) { a[j] += b2f(v0[j]); b[j] += b2f(v1[j]); }
#pragma unroll
    for (int j = 0; j < 8; ++j) { a[j] += b2f(v2[j]); b[j] += b2f(v3[j]); }
  }
  for (; p < end; ++p) {
    const int r0 = ntl_i32(&idx[p]);
    u16x8 v0 = *reinterpret_cast<const u16x8*>(&table[(size_t)r0 * tstride + cl]);
#pragma unroll
    for (int j = 0; j < 8; ++j) a[j] += b2f(v0[j]);
  }
  u16x8 o;
#pragma unroll
  for (int j = 0; j < 8; ++j) o[j] = f2b((a[j] + b[j]) * sc);
  nts_u16x8(&out[(size_t)node * ostride + cl], o);
}

// add-slice16 f32 +=: 16 cols, 2 lanes/node, 128 nodes/block
__device__ __forceinline__ void gather_add_slice16_f32(
    const unsigned short* __restrict__ table, int tstride,
    const int* __restrict__ off, const int* __restrict__ idx,
    float* __restrict__ out, int ostride, int n, int col0, int chunk) {
  const int t = threadIdx.x;
  const int g = t >> 1;
  const int cl = col0 + (t & 1) * 8;
  const int node = chunk * 128 + g;
  if (node >= n) return;
  const int beg = ntl_i32(&off[node]), end = ntl_i32(&off[node + 1]);
  const float sc = 1.0f / fmaxf((float)(end - beg), 1.0f);
  float a[8] = {0, 0, 0, 0, 0, 0, 0, 0}, b[8] = {0, 0, 0, 0, 0, 0, 0, 0};
  int p = beg;
  for (; p + 3 < end; p += 4) {
    const int r0 = ntl_i32(&idx[p]), r1 = ntl_i32(&idx[p + 1]);
    const int r2 = ntl_i32(&idx[p + 2]), r3 = ntl_i32(&idx[p + 3]);
    u16x8 v0 = *reinterpret_cast<const u16x8*>(&table[(size_t)r0 * tstride + cl]);
    u16x8 v1 = *reinterpret_cast<const u16x8*>(&table[(size_t)r1 * tstride + cl]);
    u16x8 v2 = *reinterpret_cast<const u16x8*>(&table[(size_t)r2 * tstride + cl]);
    u16x8 v3 = *reinterpret_cast<const u16x8*>(&table[(size_t)r3 * tstride + cl]);
#pragma unroll
    for (int j = 0; j < 8; ++j) { a[j] += b2f(v0[j]); b[j] += b2f(v1[j]); }
#pragma unroll
    for (int j = 0; j < 8; ++j) { a[j] += b2f(v2[j]); b[j] += b2f(v3[j]); }
  }
  for (; p < end; ++p) {
    const int r0 = ntl_i32(&idx[p]);
    u16x8 v0 = *reinterpret_cast<const u16x8*>(&table[(size_t)r0 * tstride + cl]);
#pragma unroll
    for (int j = 0; j < 8; ++j) a[j] += b2f(v0[j]);
  }
  float* dst = &out[(size_t)node * ostride + cl];
  f32x4 o0 = *reinterpret_cast<const f32x4*>(dst);
  f32x4 o1 = *reinterpret_cast<const f32x4*>(dst + 4);
#pragma unroll
  for (int j = 0; j < 4; ++j) o0[j] += (a[j] + b[j]) * sc;
#pragma unroll
  for (int j = 0; j < 4; ++j) o1[j] += (a[j + 4] + b[j + 4]) * sc;
  nts_f32x4(dst, o0);
  nts_f32x4(dst + 4, o1);
}

// gatherA: [0,12504): M1u (8 slices x 32 cols, slice = b%8 -> XCD-pinned);
//          [12504,13760): M1m (8 slices x 16 cols)
__global__ __launch_bounds__(256) void gatherA_kernel(
    const unsigned short* __restrict__ t1, const int* __restrict__ off_u,
    const int* __restrict__ csr_u, unsigned short* __restrict__ M1u,
    const unsigned short* __restrict__ xu, const int* __restrict__ off_m,
    const int* __restrict__ csr_m, unsigned short* __restrict__ xmcat) {
  if (blockIdx.x < 12504) {
    const int s = blockIdx.x & 7;
    const int chunk = blockIdx.x >> 3;  // 0..1562
    gather_slice32_b16(t1, 256, off_u, csr_u, M1u, 256, NU, s * 32, chunk);
  } else {
    const int b = blockIdx.x - 12504;
    const int s = b & 7;
    const int chunk = b >> 3;  // 0..156
    gather_slice16_b16(xu, 128, off_m, csr_m, xmcat, XMW, NM, s * 16, chunk);
  }
}

// gemmA: blocks [0,314) mode0 h_movie; rest 1564 mode1 h_user
__global__ __launch_bounds__(256) void gemmA_kernel(
    const unsigned short* __restrict__ xmcat, const unsigned short* __restrict__ wL1,
    const float* __restrict__ b1_rm, unsigned short* __restrict__ hm,
    const unsigned short* __restrict__ xu, const unsigned short* __restrict__ w1mur,
    const unsigned short* __restrict__ M1u, const float* __restrict__ b1_mu,
    unsigned short* __restrict__ hu) {
  __shared__ unsigned short Alds[128 * 32];
  __shared__ unsigned short Blds[128 * 32];
  if (blockIdx.x < 314) {
    int bi = blockIdx.x;
    gemm_core<0>(xmcat, XMW, wL1, XMW, XMW, nullptr, b1_rm, hm, NM,
                 bi % 157, bi / 157, Alds, Blds);
  } else {
    int bi = blockIdx.x - 314;
    gemm_core<1>(xu, 128, w1mur, 128, 128, M1u, b1_mu, hu, NU,
                 bi % 782, bi / 782, Alds, Blds);
  }
}

// gemmB2: [0,782) hul; [782,939) t2; [939,1721) pre_user; [1721,1878) pre_movie
__global__ __launch_bounds__(256) void gemmB2_kernel(
    const unsigned short* __restrict__ hu, const unsigned short* __restrict__ w2rml,
    unsigned short* __restrict__ hul,
    const unsigned short* __restrict__ hm, const unsigned short* __restrict__ w2mul,
    unsigned short* __restrict__ t2,
    const unsigned short* __restrict__ w2mur, const float* __restrict__ b2_mu,
    float* __restrict__ out_user,
    const unsigned short* __restrict__ w2rmr, const float* __restrict__ b2_rm,
    float* __restrict__ out_movie) {
  __shared__ unsigned short Alds[128 * 32];
  __shared__ unsigned short Blds[128 * 32];
  if (blockIdx.x < 782) {
    gemm_core<2>(hu, 256, w2rml, 256, 256, nullptr, nullptr, hul, NU,
                 blockIdx.x, 0, Alds, Blds);
  } else if (blockIdx.x < 939) {
    gemm_core<2>(hm, 256, w2mul, 256, 256, nullptr, nullptr, t2, NM,
                 blockIdx.x - 782, 0, Alds, Blds);
  } else if (blockIdx.x < 1721) {
    gemm_core<6>(hu, 256, w2mur, 256, 256, nullptr, b2_mu, out_user, NU,
                 blockIdx.x - 939, 0, Alds, Blds);
  } else {
    gemm_core<6>(hm, 256, w2rmr, 256, 256, nullptr, b2_rm, out_movie, NM,
                 blockIdx.x - 1721, 0, Alds, Blds);
  }
}

// gatherBC: [0,6256): M2u (8 slices x 16 cols) += out_user;
//           [6256,7512): M2m (8 slices x 16 cols) += out_movie
__global__ __launch_bounds__(256) void gatherBC_kernel(
    const unsigned short* __restrict__ t2, const int* __restrict__ off_u,
    const int* __restrict__ csr_u, float* __restrict__ out_user,
    const unsigned short* __restrict__ hul, const int* __restrict__ off_m,
    const int* __restrict__ csr_m, float* __restrict__ out_movie) {
  if (blockIdx.x < 6256) {
    const int s = blockIdx.x & 7;
    const int chunk = blockIdx.x >> 3;  // 0..781
    gather_add_slice16_f32(t2, 128, off_u, csr_u, out_user, 128, NU, s * 16, chunk);
  } else {
    const int b = blockIdx.x - 6256;
    const int s = b & 7;
    const int chunk = b >> 3;  // 0..156
    gather_add_slice16_f32(hul, 128, off_m, csr_m, out_movie, 128, NM, s * 16, chunk);
  }
}

extern "C" void kernel_launch(void* const* d_in, const int* in_sizes, int n_in,
                              void* d_out, int out_size, void* d_ws, size_t ws_size,
                              hipStream_t stream) {
  const float* x_user  = (const float*)d_in[0];
  const float* x_movie = (const float*)d_in[1];
  const int*   esrc    = (const int*)d_in[2];
  const int*   edst    = (const int*)d_in[3];
  const float* w1_rm_l = (const float*)d_in[4];
  const float* b1_rm   = (const float*)d_in[5];
  const float* w1_rm_r = (const float*)d_in[6];
  const float* w1_mu_l = (const float*)d_in[7];
  const float* b1_mu   = (const float*)d_in[8];
  const float* w1_mu_r = (const float*)d_in[9];
  const float* w2_rm_l = (const float*)d_in[10];
  const float* b2_rm   = (const float*)d_in[11];
  const float* w2_rm_r = (const float*)d_in[12];
  const float* w2_mu_l = (const float*)d_in[13];
  const float* b2_mu   = (const float*)d_in[14];
  const float* w2_mu_r = (const float*)d_in[15];

  if (ws_size < 214240008ull) return;
  char* wsb = (char*)d_ws;
  unsigned short* xu_bf  = (unsigned short*)(wsb + 0);           // 100000x128
  unsigned short* xmcat  = (unsigned short*)(wsb + 25600000);    // 20000x544
  unsigned short* hm_bf  = (unsigned short*)(wsb + 47360000);    // 20000x256
  unsigned short* t1_bf  = (unsigned short*)(wsb + 57600000);    // 20000x256
  unsigned short* t2_bf  = (unsigned short*)(wsb + 67840000);    // 20000x128
  unsigned short* M1u_bf = (unsigned short*)(wsb + 72960000);    // 100000x256
  unsigned short* hul_bf = (unsigned short*)(wsb + 72960000);    // 100000x128 (aliases M1u, dead)
  unsigned short* hu_bf  = (unsigned short*)(wsb + 149760000);   // 100000x256
  int* ebuf_m = (int*)(wsb + 149760000);                         // 1M ints (dead before hu write)
  int* ebuf_u = (int*)(wsb + 153760000);                         // 1M ints
  unsigned short* wts = (unsigned short*)(wsb + 200960000);
  unsigned short* wL1_t   = wts;            // 512x544
  unsigned short* w1mur_t = wts + 278528;   // 256x128
  unsigned short* wL2u_t  = wts + 311296;   // 256x256 [w2_rm_l | w2_mu_r]
  unsigned short* w2mul_t = wts + 376832;   // 128x256
  unsigned short* w2rmr_t = wts + 409600;   // 128x256
  int* iw     = (int*)(wsb + 201844736);
  int* cnt_m  = iw;                  // 64*313
  int* base_m = iw + 20032;
  int* cnt_u  = iw + 40064;          // 64*196
  int* base_u = iw + 52608;
  int* bo_m   = iw + 65152;          // 314
  int* bo_u   = iw + 65466;          // 197
  int* off_m  = iw + 120000;         // 20001 (+pad)
  int* off_u  = iw + 140004;         // 100001 (+pad)
  int* csr_m  = iw + 240008;         // 1M
  int* csr_u  = iw + 1240008;        // 1M

  float* out_movie = (float*)d_out;
  float* out_user  = (float*)d_out + (size_t)NM * OUTDIM;

  // 1) passA: bucket counts || prep
  passA_kernel<<<2 * NBLK + (PRC + 255) / 256, 256, 0, stream>>>(
      esrc, edst, cnt_m, cnt_u,
      x_user, xu_bf, x_movie, xmcat,
      w1_rm_l, w1_rm_r, w1_mu_l, w1_mu_r, w2_rm_l, w2_mu_r, w2_mu_l, w2_rm_r,
      wL1_t, w1mur_t, wL2u_t, w2mul_t, w2rmr_t);

  // 2) scanAB
  scanAB_kernel<<<2, 256, 0, stream>>>(cnt_m, base_m, bo_m, cnt_u, base_u, bo_u);

  // 3) passB: bucket-scatter || t1 GEMM
  passB_kernel<<<2 * NBLK + 314, 256, 0, stream>>>(
      esrc, edst, base_m, base_u, ebuf_m, ebuf_u,
      xmcat + 128, wL1_t + 256 * XMW + 128, t1_bf);

  // 4) passC: per-bucket CSR + off
  passC_kernel<<<NBKT_M + NBKT_U, 256, 0, stream>>>(
      ebuf_m, bo_m, off_m, csr_m, ebuf_u, bo_u, off_u, csr_u);

  // 5) gatherA: XCD-pinned slices (M1u || M1m)
  gatherA_kernel<<<12504 + 1256, 256, 0, stream>>>(
      t1_bf, off_u, csr_u, M1u_bf, xu_bf, off_m, csr_m, xmcat);

  // 6) gemmA: h_movie || h_user
  gemmA_kernel<<<314 + 1564, 256, 0, stream>>>(
      xmcat, wL1_t, b1_rm, hm_bf, xu_bf, w1mur_t, M1u_bf, b1_mu, hu_bf);

  // 7) gemmB2: hul || t2 || pre_user || pre_movie
  gemmB2_kernel<<<1878, 256, 0, stream>>>(
      hu_bf, wL2u_t, hul_bf, hm_bf, w2mul_t, t2_bf,
      wL2u_t + 128 * 256, b2_mu, out_user, w2rmr_t, b2_rm, out_movie);

  // 8) gatherBC: XCD-pinned slices += mean into outputs
  gatherBC_kernel<<<6256 + 1256, 256, 0, stream>>>(
      t2_bf, off_u, csr_u, out_user, hul_bf, off_m, csr_m, out_movie);
}

// Round 13
// 401.285 us; speedup vs baseline: 2.0692x; 2.0692x over previous
//
#include <hip/hip_runtime.h>
#include <cstddef>
#include <cstdint>

#define E_EDGES 1000000
#define NU 100000
#define NM 20000
#define DU 128
#define DM 404      // D_MOVIE
#define HIDDIM 256
#define OUTDIM 128
#define XMW 544     // concat row width: 128 + 404 + 12 pad  (17*32)

// CSR build (bucketed counting sort, no global atomics)
#define NBLK 64
#define EPB 15625
#define NBKT_M 313
#define NBKT_U 196

typedef short bf8_t __attribute__((ext_vector_type(8)));
typedef float f32x4 __attribute__((ext_vector_type(4)));
typedef unsigned short u16x8 __attribute__((ext_vector_type(8)));

__device__ __forceinline__ float b2f(unsigned short u) {
  union { unsigned int i; float f; } x; x.i = ((unsigned int)u) << 16; return x.f;
}
__device__ __forceinline__ unsigned short f2b(float f) {
  union { float f; unsigned int i; } x; x.f = f;
  unsigned int r = x.i + 0x7FFFu + ((x.i >> 16) & 1u);  // RTNE
  return (unsigned short)(r >> 16);
}

#define GLOAD_LDS16(gp, lp)                                                      \
  __builtin_amdgcn_global_load_lds(                                              \
      (const __attribute__((address_space(1))) unsigned int*)(gp),               \
      (__attribute__((address_space(3))) unsigned int*)(lp), 16, 0, 0)

// ================= passA: bucket counts (blocks 0..127) + prep (rest) =================
#define PRA 3200000
#define PRB 5280000
#define PRC 5722368
__global__ __launch_bounds__(256) void passA_kernel(
    const int* __restrict__ esrc, const int* __restrict__ edst,
    int* __restrict__ cnt_m, int* __restrict__ cnt_u,
    const float* __restrict__ x_user, unsigned short* __restrict__ xu_bf,
    const float* __restrict__ x_movie, unsigned short* __restrict__ xmcat,
    const float* __restrict__ w1_rm_l, const float* __restrict__ w1_rm_r,
    const float* __restrict__ w1_mu_l, const float* __restrict__ w1_mu_r,
    const float* __restrict__ w2_rm_l, const float* __restrict__ w2_mu_r,
    const float* __restrict__ w2_mu_l, const float* __restrict__ w2_rm_r,
    unsigned short* __restrict__ wL1, unsigned short* __restrict__ w1mur,
    unsigned short* __restrict__ wL2u, unsigned short* __restrict__ w2mul,
    unsigned short* __restrict__ w2rmr) {
  __shared__ int hist[NBKT_M];
  const int bx = blockIdx.x;
  if (bx < NBLK) {
    for (int i = threadIdx.x; i < NBKT_M; i += 256) hist[i] = 0;
    __syncthreads();
    const int base = bx * EPB, end = base + EPB;
    for (int i = base + threadIdx.x; i < end; i += 256)
      atomicAdd(&hist[edst[i] >> 6], 1);
    __syncthreads();
    for (int i = threadIdx.x; i < NBKT_M; i += 256)
      cnt_m[bx * NBKT_M + i] = hist[i];
    return;
  }
  if (bx < 2 * NBLK) {
    const int b = bx - NBLK;
    for (int i = threadIdx.x; i < NBKT_U; i += 256) hist[i] = 0;
    __syncthreads();
    const int base = b * EPB, end = base + EPB;
    for (int i = base + threadIdx.x; i < end; i += 256)
      atomicAdd(&hist[esrc[i] >> 9], 1);
    __syncthreads();
    for (int i = threadIdx.x; i < NBKT_U; i += 256)
      cnt_u[b * NBKT_U + i] = hist[i];
    return;
  }
  int j = (bx - 2 * NBLK) * 256 + threadIdx.x;
  if (j < PRA) {
    float4 v = reinterpret_cast<const float4*>(x_user)[j];
    ushort4 o;
    o.x = f2b(v.x); o.y = f2b(v.y); o.z = f2b(v.z); o.w = f2b(v.w);
    reinterpret_cast<ushort4*>(xu_bf)[j] = o;
  } else if (j < PRB) {
    int q = j - PRA;
    int row = q / 104, c4 = (q % 104) * 4;
    ushort4 o;
    if (c4 < DM) {
      float4 v = *reinterpret_cast<const float4*>(&x_movie[(size_t)row * DM + c4]);
      o.x = f2b(v.x); o.y = f2b(v.y); o.z = f2b(v.z); o.w = f2b(v.w);
    } else {
      o.x = o.y = o.z = o.w = 0;
    }
    *reinterpret_cast<ushort4*>(&xmcat[(size_t)row * XMW + 128 + c4]) = o;
  } else if (j < PRC) {
    int q = j - PRB;
    if (q < 278528) {
      int n = q / 544, k = q % 544;
      float v = 0.f;
      if (n < 256) {
        if (k < 128) v = w1_rm_l[(size_t)k * 256 + n];
        else if (k < 532) v = w1_rm_r[(size_t)(k - 128) * 256 + n];
      } else {
        if (k >= 128 && k < 532) v = w1_mu_l[(size_t)(k - 128) * 256 + (n - 256)];
      }
      wL1[q] = f2b(v);
    } else if (q < 311296) {
      int p = q - 278528; int n = p / 128, k = p % 128;
      w1mur[p] = f2b(w1_mu_r[(size_t)k * 256 + n]);
    } else if (q < 376832) {
      int p = q - 311296; int n = p / 256, k = p % 256;
      float v = (n < 128) ? w2_rm_l[(size_t)k * 128 + n] : w2_mu_r[(size_t)k * 128 + (n - 128)];
      wL2u[p] = f2b(v);
    } else if (q < 409600) {
      int p = q - 376832; int n = p / 256, k = p % 256;
      w2mul[p] = f2b(w2_mu_l[(size_t)k * 128 + n]);
    } else {
      int p = q - 409600; int n = p / 256, k = p % 256;
      w2rmr[p] = f2b(w2_rm_r[(size_t)k * 128 + n]);
    }
  }
}

// ================= scanAB =================
__global__ __launch_bounds__(256) void scanAB_kernel(
    int* __restrict__ cnt_m, int* __restrict__ base_m, int* __restrict__ bo_m,
    int* __restrict__ cnt_u, int* __restrict__ base_u, int* __restrict__ bo_u) {
  const int NB = blockIdx.x ? NBKT_U : NBKT_M;
  const int* cnt = blockIdx.x ? cnt_u : cnt_m;
  int* basep = blockIdx.x ? base_u : base_m;
  int* bo = blockIdx.x ? bo_u : bo_m;
  __shared__ int tot[NBKT_M];
  for (int B = threadIdx.x; B < NB; B += 256) {
    int s = 0;
    for (int b = 0; b < NBLK; ++b) {
      int c = cnt[b * NB + B];
      basep[b * NB + B] = s;
      s += c;
    }
    tot[B] = s;
  }
  __syncthreads();
  if (threadIdx.x < 64) {
    const int lane = threadIdx.x;
    int carry = 0;
    for (int c0 = 0; c0 < NB; c0 += 64) {
      int v = (c0 + lane < NB) ? tot[c0 + lane] : 0;
      int s = v;
#pragma unroll
      for (int d = 1; d < 64; d <<= 1) {
        int t = __shfl_up(s, d, 64);
        if (lane >= d) s += t;
      }
      if (c0 + lane < NB) bo[c0 + lane] = carry + s - v;
      carry += __shfl(s, 63, 64);
    }
    if (lane == 0) bo[NB] = carry;
  }
  __syncthreads();
  for (int B = threadIdx.x; B < NB; B += 256) {
    const int b0 = bo[B];
    for (int b = 0; b < NBLK; ++b) basep[b * NB + B] += b0;
  }
}

// ================= shared GEMM core =================
template <int MODE>
__device__ __forceinline__ void gemm_core(
    const unsigned short* __restrict__ A, int lda,
    const unsigned short* __restrict__ Bt, int ldb, int K,
    const unsigned short* __restrict__ elem, const float* __restrict__ bias,
    void* __restrict__ outA, int M, int bx, int by,
    unsigned short* Alds, unsigned short* Blds) {
  const int tid = threadIdx.x;
  const int w = tid >> 6, l = tid & 63;
  const int row0 = bx * 128;
  const int col0 = by * 128;
  const int wr = w >> 1, wc = w & 1;

  f32x4 acc[4][4] = {};

  int ar0 = row0 + w * 32 + (l >> 2);
  int ar1 = ar0 + 16;
  if (ar0 >= M) ar0 = M - 1;
  if (ar1 >= M) ar1 = M - 1;
  const size_t aoff0 = (size_t)ar0 * lda + (l & 3) * 8;
  const size_t aoff1 = (size_t)ar1 * lda + (l & 3) * 8;
  const int nr0 = col0 + w * 32 + (l >> 2);
  const size_t boff0 = (size_t)nr0 * ldb + (l & 3) * 8;
  const size_t boff1 = (size_t)(nr0 + 16) * ldb + (l & 3) * 8;
  unsigned short* aldsb = &Alds[w * 1024];
  unsigned short* bldsb = &Blds[w * 1024];

  for (int k0 = 0; k0 < K; k0 += 32) {
    GLOAD_LDS16(A + aoff0 + k0, aldsb);
    GLOAD_LDS16(A + aoff1 + k0, aldsb + 512);
    GLOAD_LDS16(Bt + boff0 + k0, bldsb);
    GLOAD_LDS16(Bt + boff1 + k0, bldsb + 512);
    __syncthreads();
    bf8_t af[4], bfr[4];
#pragma unroll
    for (int mi = 0; mi < 4; ++mi)
      af[mi] = *reinterpret_cast<const bf8_t*>(&Alds[(wr * 64 + mi * 16 + (l & 15)) * 32 + (l >> 4) * 8]);
#pragma unroll
    for (int nj = 0; nj < 4; ++nj)
      bfr[nj] = *reinterpret_cast<const bf8_t*>(&Blds[(wc * 64 + nj * 16 + (l & 15)) * 32 + (l >> 4) * 8]);
#pragma unroll
    for (int mi = 0; mi < 4; ++mi)
#pragma unroll
      for (int nj = 0; nj < 4; ++nj)
        acc[mi][nj] = __builtin_amdgcn_mfma_f32_16x16x32_bf16(af[mi], bfr[nj], acc[mi][nj], 0, 0, 0);
    __syncthreads();
  }

#pragma unroll
  for (int mi = 0; mi < 4; ++mi) {
    const int rbase = row0 + wr * 64 + mi * 16 + ((l >> 4) << 2);
#pragma unroll
    for (int nj = 0; nj < 4; ++nj) {
      const int col = col0 + wc * 64 + nj * 16 + (l & 15);
      float bb = 0.0f;
      if constexpr (MODE == 0 || MODE == 1 || MODE == 6) bb = bias[col];
#pragma unroll
      for (int r = 0; r < 4; ++r) {
        const int row = rbase + r;
        if (row >= M) continue;
        float v = acc[mi][nj][r] + bb;
        if constexpr (MODE == 1) v += b2f(elem[(size_t)row * 256 + col]);
        if constexpr (MODE == 0 || MODE == 1) v = fmaxf(v, 0.0f);
        if constexpr (MODE == 0 || MODE == 1 || MODE == 5) {
          ((unsigned short*)outA)[(size_t)row * 256 + col] = f2b(v);
        } else if constexpr (MODE == 2) {
          ((unsigned short*)outA)[(size_t)row * 128 + col] = f2b(v);
        } else {
          ((float*)outA)[(size_t)row * 128 + col] = v;
        }
      }
    }
  }
}

// ================= passB: bucket-scatter (blocks 0..127) + t1 GEMM (rest) =================
__global__ __launch_bounds__(256) void passB_kernel(
    const int* __restrict__ esrc, const int* __restrict__ edst,
    const int* __restrict__ base_m, const int* __restrict__ base_u,
    int* __restrict__ ebuf_m, int* __restrict__ ebuf_u,
    const unsigned short* __restrict__ A, const unsigned short* __restrict__ Bt,
    unsigned short* __restrict__ t1) {
  __shared__ unsigned short Alds[128 * 32];
  __shared__ unsigned short Blds[128 * 32];
  const int bx = blockIdx.x;
  if (bx < NBLK) {
    int* cur = (int*)Alds;
    for (int i = threadIdx.x; i < NBKT_M; i += 256) cur[i] = base_m[bx * NBKT_M + i];
    __syncthreads();
    const int base = bx * EPB, end = base + EPB;
    for (int i = base + threadIdx.x; i < end; i += 256) {
      const int d = edst[i], s = esrc[i];
      const int pos = atomicAdd(&cur[d >> 6], 1);
      ebuf_m[pos] = (s << 6) | (d & 63);
    }
    return;
  }
  if (bx < 2 * NBLK) {
    const int b = bx - NBLK;
    int* cur = (int*)Alds;
    for (int i = threadIdx.x; i < NBKT_U; i += 256) cur[i] = base_u[b * NBKT_U + i];
    __syncthreads();
    const int base = b * EPB, end = base + EPB;
    for (int i = base + threadIdx.x; i < end; i += 256) {
      const int d = edst[i], s = esrc[i];
      const int pos = atomicAdd(&cur[s >> 9], 1);
      ebuf_u[pos] = (d << 9) | (s & 511);
    }
    return;
  }
  const int bi = bx - 2 * NBLK;
  gemm_core<5>(A, XMW, Bt, XMW, 416, nullptr, nullptr, t1, NM,
               bi % 157, bi / 157, Alds, Blds);
}

// ================= passC: per-bucket CSR + off =================
__global__ __launch_bounds__(256) void passC_kernel(
    const int* __restrict__ ebuf_m, const int* __restrict__ bo_m,
    int* __restrict__ off_m, int* __restrict__ csr_m,
    const int* __restrict__ ebuf_u, const int* __restrict__ bo_u,
    int* __restrict__ off_u, int* __restrict__ csr_u) {
  __shared__ int hist[512];
  const int bx = blockIdx.x;
  if (bx < NBKT_M) {
    const int B = bx;
    const int lo = bo_m[B], hi = bo_m[B + 1];
    const int nbin = (NM - B * 64 < 64) ? (NM - B * 64) : 64;
    for (int i = threadIdx.x; i < 64; i += 256) hist[i] = 0;
    __syncthreads();
    for (int i = lo + threadIdx.x; i < hi; i += 256)
      atomicAdd(&hist[ebuf_m[i] & 63], 1);
    __syncthreads();
    if (threadIdx.x < 64) {
      const int lane = threadIdx.x;
      const int v = hist[lane];
      int s = v;
#pragma unroll
      for (int d = 1; d < 64; d <<= 1) {
        int t = __shfl_up(s, d, 64);
        if (lane >= d) s += t;
      }
      const int ex = s - v;
      if (lane < nbin) off_m[B * 64 + lane] = lo + ex;
      if (B == NBKT_M - 1 && lane == 0) off_m[NM] = hi;
      hist[lane] = ex;
    }
    __syncthreads();
    for (int i = lo + threadIdx.x; i < hi; i += 256) {
      const int p = ebuf_m[i];
      const int pos = atomicAdd(&hist[p & 63], 1);
      csr_m[lo + pos] = p >> 6;
    }
    return;
  }
  const int B = bx - NBKT_M;
  const int lo = bo_u[B], hi = bo_u[B + 1];
  const int nbin = (NU - B * 512 < 512) ? (NU - B * 512) : 512;
  for (int i = threadIdx.x; i < 512; i += 256) hist[i] = 0;
  __syncthreads();
  for (int i = lo + threadIdx.x; i < hi; i += 256)
    atomicAdd(&hist[ebuf_u[i] & 511], 1);
  __syncthreads();
  if (threadIdx.x < 64) {
    const int lane = threadIdx.x;
    int carry = 0;
    for (int c0 = 0; c0 < 512; c0 += 64) {
      const int v = hist[c0 + lane];
      int s = v;
#pragma unroll
      for (int d = 1; d < 64; d <<= 1) {
        int t = __shfl_up(s, d, 64);
        if (lane >= d) s += t;
      }
      const int ex = carry + s - v;
      if (c0 + lane < nbin) off_u[B * 512 + c0 + lane] = lo + ex;
      hist[c0 + lane] = ex;
      carry += __shfl(s, 63, 64);
    }
    if (B == NBKT_U - 1 && lane == 0) off_u[NU] = hi;
  }
  __syncthreads();
  for (int i = lo + threadIdx.x; i < hi; i += 256) {
    const int p = ebuf_u[i];
    const int pos = atomicAdd(&hist[p & 511], 1);
    csr_u[lo + pos] = p >> 9;
  }
}

// ================= gather core (full row, bf16 out) =================
template <int D>
__device__ __forceinline__ void gather_core(
    const unsigned short* __restrict__ table, const int* __restrict__ off,
    const int* __restrict__ idx, unsigned short* __restrict__ out,
    int n, int ostride, int bi) {
  constexpr int LPN = D / 8;
  constexpr int NPB = 256 / LPN;
  const int t = threadIdx.x;
  const int g = t / LPN;
  const int cl = (t % LPN) * 8;
  const int node = bi * NPB + g;
  if (node >= n) return;
  const int beg = off[node], end = off[node + 1];
  const float sc = 1.0f / fmaxf((float)(end - beg), 1.0f);
  float a[8] = {0, 0, 0, 0, 0, 0, 0, 0}, b[8] = {0, 0, 0, 0, 0, 0, 0, 0};
  int p = beg;
  for (; p + 3 < end; p += 4) {
    const int r0 = idx[p], r1 = idx[p + 1], r2 = idx[p + 2], r3 = idx[p + 3];
    u16x8 v0 = *reinterpret_cast<const u16x8*>(&table[(size_t)r0 * D + cl]);
    u16x8 v1 = *reinterpret_cast<const u16x8*>(&table[(size_t)r1 * D + cl]);
    u16x8 v2 = *reinterpret_cast<const u16x8*>(&table[(size_t)r2 * D + cl]);
    u16x8 v3 = *reinterpret_cast<const u16x8*>(&table[(size_t)r3 * D + cl]);
#pragma unroll
    for (int j = 0; j < 8; ++j) { a[j] += b2f(v0[j]); b[j] += b2f(v1[j]); }
#pragma unroll
    for (int j = 0; j < 8; ++j) { a[j] += b2f(v2[j]); b[j] += b2f(v3[j]); }
  }
  for (; p < end; ++p) {
    const int r0 = idx[p];
    u16x8 v0 = *reinterpret_cast<const u16x8*>(&table[(size_t)r0 * D + cl]);
#pragma unroll
    for (int j = 0; j < 8; ++j) a[j] += b2f(v0[j]);
  }
  u16x8 o;
#pragma unroll
  for (int j = 0; j < 8; ++j) o[j] = f2b((a[j] + b[j]) * sc);
  *reinterpret_cast<u16x8*>(&out[(size_t)node * ostride + cl]) = o;
}

// ================= gather slice (64 cols = 128B/row, bf16 out) =================
__device__ __forceinline__ void gather_slice64(
    const unsigned short* __restrict__ table, int tstride,
    const int* __restrict__ off, const int* __restrict__ idx,
    unsigned short* __restrict__ out, int ostride, int n, int col0, int bi) {
  const int t = threadIdx.x;
  const int g = t >> 3;
  const int cl = col0 + (t & 7) * 8;
  const int node = bi * 32 + g;
  if (node >= n) return;
  const int beg = off[node], end = off[node + 1];
  const float sc = 1.0f / fmaxf((float)(end - beg), 1.0f);
  float a[8] = {0, 0, 0, 0, 0, 0, 0, 0}, b[8] = {0, 0, 0, 0, 0, 0, 0, 0};
  int p = beg;
  for (; p + 3 < end; p += 4) {
    const int r0 = idx[p], r1 = idx[p + 1], r2 = idx[p + 2], r3 = idx[p + 3];
    u16x8 v0 = *reinterpret_cast<const u16x8*>(&table[(size_t)r0 * tstride + cl]);
    u16x8 v1 = *reinterpret_cast<const u16x8*>(&table[(size_t)r1 * tstride + cl]);
    u16x8 v2 = *reinterpret_cast<const u16x8*>(&table[(size_t)r2 * tstride + cl]);
    u16x8 v3 = *reinterpret_cast<const u16x8*>(&table[(size_t)r3 * tstride + cl]);
#pragma unroll
    for (int j = 0; j < 8; ++j) { a[j] += b2f(v0[j]); b[j] += b2f(v1[j]); }
#pragma unroll
    for (int j = 0; j < 8; ++j) { a[j] += b2f(v2[j]); b[j] += b2f(v3[j]); }
  }
  for (; p < end; ++p) {
    const int r0 = idx[p];
    u16x8 v0 = *reinterpret_cast<const u16x8*>(&table[(size_t)r0 * tstride + cl]);
#pragma unroll
    for (int j = 0; j < 8; ++j) a[j] += b2f(v0[j]);
  }
  u16x8 o;
#pragma unroll
  for (int j = 0; j < 8; ++j) o[j] = f2b((a[j] + b[j]) * sc);
  *reinterpret_cast<u16x8*>(&out[(size_t)node * ostride + cl]) = o;
}

// ================= gather-add slice (64 cols, f32 += mean) =================
__device__ __forceinline__ void gather_add_slice64(
    const unsigned short* __restrict__ table, int tstride,
    const int* __restrict__ off, const int* __restrict__ idx,
    float* __restrict__ out, int ostride, int n, int col0, int bi) {
  const int t = threadIdx.x;
  const int g = t >> 3;
  const int cl = col0 + (t & 7) * 8;
  const int node = bi * 32 + g;
  if (node >= n) return;
  const int beg = off[node], end = off[node + 1];
  const float sc = 1.0f / fmaxf((float)(end - beg), 1.0f);
  float a[8] = {0, 0, 0, 0, 0, 0, 0, 0}, b[8] = {0, 0, 0, 0, 0, 0, 0, 0};
  int p = beg;
  for (; p + 3 < end; p += 4) {
    const int r0 = idx[p], r1 = idx[p + 1], r2 = idx[p + 2], r3 = idx[p + 3];
    u16x8 v0 = *reinterpret_cast<const u16x8*>(&table[(size_t)r0 * tstride + cl]);
    u16x8 v1 = *reinterpret_cast<const u16x8*>(&table[(size_t)r1 * tstride + cl]);
    u16x8 v2 = *reinterpret_cast<const u16x8*>(&table[(size_t)r2 * tstride + cl]);
    u16x8 v3 = *reinterpret_cast<const u16x8*>(&table[(size_t)r3 * tstride + cl]);
#pragma unroll
    for (int j = 0; j < 8; ++j) { a[j] += b2f(v0[j]); b[j] += b2f(v1[j]); }
#pragma unroll
    for (int j = 0; j < 8; ++j) { a[j] += b2f(v2[j]); b[j] += b2f(v3[j]); }
  }
  for (; p < end; ++p) {
    const int r0 = idx[p];
    u16x8 v0 = *reinterpret_cast<const u16x8*>(&table[(size_t)r0 * tstride + cl]);
#pragma unroll
    for (int j = 0; j < 8; ++j) a[j] += b2f(v0[j]);
  }
  float* dst = &out[(size_t)node * ostride + cl];
  float4 o0 = *reinterpret_cast<const float4*>(dst);
  float4 o1 = *reinterpret_cast<const float4*>(dst + 4);
  o0.x += (a[0] + b[0]) * sc; o0.y += (a[1] + b[1]) * sc;
  o0.z += (a[2] + b[2]) * sc; o0.w += (a[3] + b[3]) * sc;
  o1.x += (a[4] + b[4]) * sc; o1.y += (a[5] + b[5]) * sc;
  o1.z += (a[6] + b[6]) * sc; o1.w += (a[7] + b[7]) * sc;
  *reinterpret_cast<float4*>(dst) = o0;
  *reinterpret_cast<float4*>(dst + 4) = o1;
}

// ================= gather-add full 128 (f32 += mean), 16 nodes/block =================
__device__ __forceinline__ void gather_add_f32_128(
    const unsigned short* __restrict__ table, const int* __restrict__ off,
    const int* __restrict__ idx, float* __restrict__ out, int n, int bi) {
  const int t = threadIdx.x;
  const int g = t >> 4;
  const int cl = (t & 15) * 8;
  const int node = bi * 16 + g;
  if (node >= n) return;
  const int beg = off[node], end = off[node + 1];
  const float sc = 1.0f / fmaxf((float)(end - beg), 1.0f);
  float a[8] = {0, 0, 0, 0, 0, 0, 0, 0}, b[8] = {0, 0, 0, 0, 0, 0, 0, 0};
  int p = beg;
  for (; p + 3 < end; p += 4) {
    const int r0 = idx[p], r1 = idx[p + 1], r2 = idx[p + 2], r3 = idx[p + 3];
    u16x8 v0 = *reinterpret_cast<const u16x8*>(&table[(size_t)r0 * 128 + cl]);
    u16x8 v1 = *reinterpret_cast<const u16x8*>(&table[(size_t)r1 * 128 + cl]);
    u16x8 v2 = *reinterpret_cast<const u16x8*>(&table[(size_t)r2 * 128 + cl]);
    u16x8 v3 = *reinterpret_cast<const u16x8*>(&table[(size_t)r3 * 128 + cl]);
#pragma unroll
    for (int j = 0; j < 8; ++j) { a[j] += b2f(v0[j]); b[j] += b2f(v1[j]); }
#pragma unroll
    for (int j = 0; j < 8; ++j) { a[j] += b2f(v2[j]); b[j] += b2f(v3[j]); }
  }
  for (; p < end; ++p) {
    const int r0 = idx[p];
    u16x8 v0 = *reinterpret_cast<const u16x8*>(&table[(size_t)r0 * 128 + cl]);
#pragma unroll
    for (int j = 0; j < 8; ++j) a[j] += b2f(v0[j]);
  }
  float* dst = &out[(size_t)node * 128 + cl];
  float4 o0 = *reinterpret_cast<const float4*>(dst);
  float4 o1 = *reinterpret_cast<const float4*>(dst + 4);
  o0.x += (a[0] + b[0]) * sc; o0.y += (a[1] + b[1]) * sc;
  o0.z += (a[2] + b[2]) * sc; o0.w += (a[3] + b[3]) * sc;
  o1.x += (a[4] + b[4]) * sc; o1.y += (a[5] + b[5]) * sc;
  o1.z += (a[6] + b[6]) * sc; o1.w += (a[7] + b[7]) * sc;
  *reinterpret_cast<float4*>(dst) = o0;
  *reinterpret_cast<float4*>(dst + 4) = o1;
}

// gatherA: blocks [0,12500): M1u sliced (4 x 3125); rest 1250: M1m full-width
__global__ __launch_bounds__(256) void gatherA_kernel(
    const unsigned short* __restrict__ t1, const int* __restrict__ off_u,
    const int* __restrict__ csr_u, unsigned short* __restrict__ M1u,
    const unsigned short* __restrict__ xu, const int* __restrict__ off_m,
    const int* __restrict__ csr_m, unsigned short* __restrict__ xmcat) {
  if (blockIdx.x < 12500) {
    const int s = blockIdx.x / 3125;
    const int bi = blockIdx.x % 3125;
    gather_slice64(t1, 256, off_u, csr_u, M1u, 256, NU, s * 64, bi);
  } else {
    gather_core<128>(xu, off_m, csr_m, xmcat, NM, XMW, blockIdx.x - 12500);
  }
}

// gemmA: blocks [0,314) mode0 h_movie; rest 1564 mode1 h_user
__global__ __launch_bounds__(256) void gemmA_kernel(
    const unsigned short* __restrict__ xmcat, const unsigned short* __restrict__ wL1,
    const float* __restrict__ b1_rm, unsigned short* __restrict__ hm,
    const unsigned short* __restrict__ xu, const unsigned short* __restrict__ w1mur,
    const unsigned short* __restrict__ M1u, const float* __restrict__ b1_mu,
    unsigned short* __restrict__ hu) {
  __shared__ unsigned short Alds[128 * 32];
  __shared__ unsigned short Blds[128 * 32];
  if (blockIdx.x < 314) {
    int bi = blockIdx.x;
    gemm_core<0>(xmcat, XMW, wL1, XMW, XMW, nullptr, b1_rm, hm, NM,
                 bi % 157, bi / 157, Alds, Blds);
  } else {
    int bi = blockIdx.x - 314;
    gemm_core<1>(xu, 128, w1mur, 128, 128, M1u, b1_mu, hu, NU,
                 bi % 782, bi / 782, Alds, Blds);
  }
}

// gemmB2: [0,782) hul; [782,939) t2; [939,1721) pre_user; [1721,1878) pre_movie
__global__ __launch_bounds__(256) void gemmB2_kernel(
    const unsigned short* __restrict__ hu, const unsigned short* __restrict__ w2rml,
    unsigned short* __restrict__ hul,
    const unsigned short* __restrict__ hm, const unsigned short* __restrict__ w2mul,
    unsigned short* __restrict__ t2,
    const unsigned short* __restrict__ w2mur, const float* __restrict__ b2_mu,
    float* __restrict__ out_user,
    const unsigned short* __restrict__ w2rmr, const float* __restrict__ b2_rm,
    float* __restrict__ out_movie) {
  __shared__ unsigned short Alds[128 * 32];
  __shared__ unsigned short Blds[128 * 32];
  if (blockIdx.x < 782) {
    gemm_core<2>(hu, 256, w2rml, 256, 256, nullptr, nullptr, hul, NU,
                 blockIdx.x, 0, Alds, Blds);
  } else if (blockIdx.x < 939) {
    gemm_core<2>(hm, 256, w2mul, 256, 256, nullptr, nullptr, t2, NM,
                 blockIdx.x - 782, 0, Alds, Blds);
  } else if (blockIdx.x < 1721) {
    gemm_core<6>(hu, 256, w2mur, 256, 256, nullptr, b2_mu, out_user, NU,
                 blockIdx.x - 939, 0, Alds, Blds);
  } else {
    gemm_core<6>(hm, 256, w2rmr, 256, 256, nullptr, b2_rm, out_movie, NM,
                 blockIdx.x - 1721, 0, Alds, Blds);
  }
}

// gatherBC: blocks [0,6250): M2u sliced (2 x 3125) += out_user; rest 1250: M2m += out_movie
__global__ __launch_bounds__(256) void gatherBC_kernel(
    const unsigned short* __restrict__ t2, const int* __restrict__ off_u,
    const int* __restrict__ csr_u, float* __restrict__ out_user,
    const unsigned short* __restrict__ hul, const int* __restrict__ off_m,
    const int* __restrict__ csr_m, float* __restrict__ out_movie) {
  if (blockIdx.x < 6250) {
    const int s = blockIdx.x / 3125;
    const int bi = blockIdx.x % 3125;
    gather_add_slice64(t2, 128, off_u, csr_u, out_user, 128, NU, s * 64, bi);
  } else {
    gather_add_f32_128(hul, off_m, csr_m, out_movie, NM, blockIdx.x - 6250);
  }
}

extern "C" void kernel_launch(void* const* d_in, const int* in_sizes, int n_in,
                              void* d_out, int out_size, void* d_ws, size_t ws_size,
                              hipStream_t stream) {
  const float* x_user  = (const float*)d_in[0];
  const float* x_movie = (const float*)d_in[1];
  const int*   esrc    = (const int*)d_in[2];
  const int*   edst    = (const int*)d_in[3];
  const float* w1_rm_l = (const float*)d_in[4];
  const float* b1_rm   = (const float*)d_in[5];
  const float* w1_rm_r = (const float*)d_in[6];
  const float* w1_mu_l = (const float*)d_in[7];
  const float* b1_mu   = (const float*)d_in[8];
  const float* w1_mu_r = (const float*)d_in[9];
  const float* w2_rm_l = (const float*)d_in[10];
  const float* b2_rm   = (const float*)d_in[11];
  const float* w2_rm_r = (const float*)d_in[12];
  const float* w2_mu_l = (const float*)d_in[13];
  const float* b2_mu   = (const float*)d_in[14];
  const float* w2_mu_r = (const float*)d_in[15];

  if (ws_size < 214240008ull) return;
  char* wsb = (char*)d_ws;
  unsigned short* xu_bf  = (unsigned short*)(wsb + 0);           // 100000x128
  unsigned short* xmcat  = (unsigned short*)(wsb + 25600000);    // 20000x544
  unsigned short* hm_bf  = (unsigned short*)(wsb + 47360000);    // 20000x256
  unsigned short* t1_bf  = (unsigned short*)(wsb + 57600000);    // 20000x256
  unsigned short* t2_bf  = (unsigned short*)(wsb + 67840000);    // 20000x128
  unsigned short* M1u_bf = (unsigned short*)(wsb + 72960000);    // 100000x256
  unsigned short* hul_bf = (unsigned short*)(wsb + 72960000);    // 100000x128 (aliases M1u, dead)
  unsigned short* hu_bf  = (unsigned short*)(wsb + 149760000);   // 100000x256
  int* ebuf_m = (int*)(wsb + 149760000);                         // 1M ints (dead before hu write)
  int* ebuf_u = (int*)(wsb + 153760000);                         // 1M ints
  unsigned short* wts = (unsigned short*)(wsb + 200960000);
  unsigned short* wL1_t   = wts;            // 512x544
  unsigned short* w1mur_t = wts + 278528;   // 256x128
  unsigned short* wL2u_t  = wts + 311296;   // 256x256 [w2_rm_l | w2_mu_r]
  unsigned short* w2mul_t = wts + 376832;   // 128x256
  unsigned short* w2rmr_t = wts + 409600;   // 128x256
  int* iw     = (int*)(wsb + 201844736);
  int* cnt_m  = iw;                  // 64*313
  int* base_m = iw + 20032;
  int* cnt_u  = iw + 40064;          // 64*196
  int* base_u = iw + 52608;
  int* bo_m   = iw + 65152;          // 314
  int* bo_u   = iw + 65466;          // 197
  int* off_m  = iw + 120000;         // 20001 (+pad)
  int* off_u  = iw + 140004;         // 100001 (+pad)
  int* csr_m  = iw + 240008;         // 1M
  int* csr_u  = iw + 1240008;        // 1M

  float* out_movie = (float*)d_out;
  float* out_user  = (float*)d_out + (size_t)NM * OUTDIM;

  // 1) passA: bucket counts || prep
  passA_kernel<<<2 * NBLK + (PRC + 255) / 256, 256, 0, stream>>>(
      esrc, edst, cnt_m, cnt_u,
      x_user, xu_bf, x_movie, xmcat,
      w1_rm_l, w1_rm_r, w1_mu_l, w1_mu_r, w2_rm_l, w2_mu_r, w2_mu_l, w2_rm_r,
      wL1_t, w1mur_t, wL2u_t, w2mul_t, w2rmr_t);

  // 2) scanAB
  scanAB_kernel<<<2, 256, 0, stream>>>(cnt_m, base_m, bo_m, cnt_u, base_u, bo_u);

  // 3) passB: bucket-scatter || t1 GEMM
  passB_kernel<<<2 * NBLK + 314, 256, 0, stream>>>(
      esrc, edst, base_m, base_u, ebuf_m, ebuf_u,
      xmcat + 128, wL1_t + 256 * XMW + 128, t1_bf);

  // 4) passC: per-bucket CSR + off
  passC_kernel<<<NBKT_M + NBKT_U, 256, 0, stream>>>(
      ebuf_m, bo_m, off_m, csr_m, ebuf_u, bo_u, off_u, csr_u);

  // 5) gatherA: M1u sliced (L2-resident slices) || M1m
  gatherA_kernel<<<12500 + 1250, 256, 0, stream>>>(
      t1_bf, off_u, csr_u, M1u_bf, xu_bf, off_m, csr_m, xmcat);

  // 6) gemmA: h_movie || h_user
  gemmA_kernel<<<314 + 1564, 256, 0, stream>>>(
      xmcat, wL1_t, b1_rm, hm_bf, xu_bf, w1mur_t, M1u_bf, b1_mu, hu_bf);

  // 7) gemmB2: hul || t2 || pre_user || pre_movie
  gemmB2_kernel<<<1878, 256, 0, stream>>>(
      hu_bf, wL2u_t, hul_bf, hm_bf, w2mul_t, t2_bf,
      wL2u_t + 128 * 256, b2_mu, out_user, w2rmr_t, b2_rm, out_movie);

  // 8) gatherBC: += mean into outputs (f32, exclusive per node)
  gatherBC_kernel<<<6250 + 1250, 256, 0, stream>>>(
      t2_bf, off_u, csr_u, out_user, hul_bf, off_m, csr_m, out_movie);
}